// Round 2
// baseline (171.345 us; speedup 1.0000x reference)
//
#include <hip/hip_runtime.h>

// GAGKNNQueryAndGroup: B=4, N=8192, NPOINT=2048, C=64, NSAMPLE=32, LAMBDA=0.5
// Inputs: xyz(B,N,3) f32 | new_xyz(B,NPOINT,3) f32 | components(B,N,1) int |
//         new_components(B,NPOINT,1) int | features(B,C,N) f32
// Output: (B, 3+C, NPOINT, NS) f32
//
// NOTE: LAMBDA == 0.5 makes the component mask numerically irrelevant:
// where(mask, d*0.5, d*0.5) == d*0.5 (exact, order-preserving). Components unused.

#define BQ 4
#define NN_ 8192
#define NPOINT 2048
#define CF 64
#define NS 32
#define T1 256
#define PER (NN_ / T1)   // 32 candidates per thread
#define CAP 1024         // candidate list capacity (expected ~34)

// ---------------- Phase 1: exact top-32 selection per query ----------------
// R1: replaced the 256-wide LDS bitonic (36 barriers) with a per-wave 64-lane
// in-register bitonic (__shfl_xor, 0 barriers); theta = min over waves of each
// wave's 32nd-smallest lane-min (each is a valid upper bound on the true 32nd
// distance: 32 of the wave's 64 lane-minima -- all actual data values -- are
// <= it; min of upper bounds is a tighter upper bound).
// Also vectorized xyz loads: 4 consecutive points = 3 aligned float4 loads.
__global__ __launch_bounds__(256) void knn_kernel(const float* __restrict__ xyz,
                                                  const float* __restrict__ new_xyz,
                                                  int* __restrict__ idxOut) {
  const int q = blockIdx.x;            // b*NPOINT + p
  const int b = q / NPOINT;
  const int tid = threadIdx.x;
  const int lane = tid & 63;
  const int wid = tid >> 6;

  const float qx = new_xyz[q * 3 + 0];
  const float qy = new_xyz[q * 3 + 1];
  const float qz = new_xyz[q * 3 + 2];

  const float* __restrict__ base = xyz + (size_t)b * NN_ * 3;

  float d[PER];
  float lmin = 3.4e38f;
#pragma unroll
  for (int j = 0; j < PER / 4; j++) {        // 8 chunks x 4 consecutive points
    const int n0 = j * 1024 + tid * 4;       // 4-point groups: 48B, 16B-aligned
    const float4* p = (const float4*)(base + (size_t)n0 * 3);
    float4 v0 = p[0];   // x0 y0 z0 x1
    float4 v1 = p[1];   // y1 z1 x2 y2
    float4 v2 = p[2];   // z2 x3 y3 z3
    float xs[4] = {v0.x, v0.w, v1.z, v2.y};
    float ys[4] = {v0.y, v1.x, v1.w, v2.z};
    float zs[4] = {v0.z, v1.y, v2.x, v2.w};
#pragma unroll
    for (int i = 0; i < 4; i++) {
      float dx = xs[i] - qx;
      float dy = ys[i] - qy;
      float dz = zs[i] - qz;
      // Match numpy f32 evaluation exactly: no FMA contraction, left-to-right sum.
      float dist = __fadd_rn(__fadd_rn(__fmul_rn(dx, dx), __fmul_rn(dy, dy)),
                             __fmul_rn(dz, dz));
      dist *= 0.5f;   // LAMBDA == 1-LAMBDA == 0.5
      d[j * 4 + i] = dist;
      lmin = fminf(lmin, dist);
    }
  }

  // Wave-level bitonic sort (ascending) of the 64 lane-minima, in registers.
  float v = lmin;
#pragma unroll
  for (int k = 2; k <= 64; k <<= 1) {
#pragma unroll
    for (int j = k >> 1; j > 0; j >>= 1) {
      float o = __shfl_xor(v, j);
      bool up = ((lane & k) == 0);       // k==64: all lanes ascending
      bool lower = ((lane & j) == 0);
      float mn = fminf(v, o), mx = fmaxf(v, o);
      v = (up == lower) ? mn : mx;
    }
  }
  // lane 31 now holds the wave's 32nd-smallest lane-min.

  __shared__ float wTheta[4];
  __shared__ unsigned long long cand[CAP];
  __shared__ int cnt;
  if (tid == 0) cnt = 0;
  if (lane == 31) wTheta[wid] = v;
  __syncthreads();
  const float theta = fminf(fminf(wTheta[0], wTheta[1]),
                            fminf(wTheta[2], wTheta[3]));

  // Collect all candidates with d <= theta (guaranteed >= 32 exist).
#pragma unroll
  for (int j = 0; j < PER / 4; j++) {
#pragma unroll
    for (int i = 0; i < 4; i++) {
      if (d[j * 4 + i] <= theta) {
        int n = j * 1024 + tid * 4 + i;
        int pos = atomicAdd(&cnt, 1);
        if (pos < CAP)
          cand[pos] = ((unsigned long long)__float_as_uint(d[j * 4 + i]) << 32) |
                      (unsigned)n;
      }
    }
  }
  __syncthreads();
  int m = cnt < CAP ? cnt : CAP;

  // Exact rank of each candidate by (dist_bits, idx) — matches stable argsort.
  for (int i = tid; i < m; i += T1) {
    unsigned long long x = cand[i];
    int r = 0;
    for (int j = 0; j < m; j++) r += (cand[j] < x) ? 1 : 0;
    if (r < NS) idxOut[q * NS + r] = (int)(x & 0xffffffffu);
  }
}

// ---------------- Phase 2: features (B,C,N) -> featsT (B,N,C) ----------------
__global__ __launch_bounds__(256) void transpose_kernel(const float* __restrict__ f,
                                                        float* __restrict__ ft) {
  __shared__ float t[32][33];
  const int b = blockIdx.z;
  const int n0 = blockIdx.x * 32;
  const int c0 = blockIdx.y * 32;
  const int tx = threadIdx.x;   // 0..31
  const int ty = threadIdx.y;   // 0..7
#pragma unroll
  for (int i = 0; i < 4; i++) {
    int c = c0 + ty + i * 8;
    t[ty + i * 8][tx] = f[(size_t)b * CF * NN_ + (size_t)c * NN_ + n0 + tx];
  }
  __syncthreads();
#pragma unroll
  for (int i = 0; i < 4; i++) {
    int nrow = n0 + ty + i * 8;
    ft[(size_t)b * NN_ * CF + (size_t)nrow * CF + c0 + tx] = t[tx][ty + i * 8];
  }
}

// ---------------- Phase 3: gather + grouped write ----------------
#define FSTR 68   // LDS row stride: multiple of 4 (float4 stores), 4-way bank alias only
__global__ __launch_bounds__(256) void group_kernel(const float* __restrict__ xyz,
                                                    const float* __restrict__ new_xyz,
                                                    const float* __restrict__ featsT,
                                                    const int* __restrict__ idxArr,
                                                    float* __restrict__ out) {
  const int q = blockIdx.x;            // b*NPOINT + p
  const int b = q / NPOINT;
  const int p = q - b * NPOINT;
  const int tid = threadIdx.x;

  __shared__ int sIdx[NS];
  __shared__ __align__(16) float ldsF[NS * FSTR];
  __shared__ float ldsX[3 * NS];

  if (tid < NS) sIdx[tid] = idxArr[q * NS + tid];
  __syncthreads();

  {
    // 256 threads = 32 samples x 8 readers; each reader pulls 32B of the
    // 256B contiguous feature row for its sample.
    int s = tid >> 3, r = tid & 7;
    int nn = sIdx[s];
    const float4* src = (const float4*)(featsT + ((size_t)b * NN_ + nn) * CF);
    float4 v0 = src[r * 2];
    float4 v1 = src[r * 2 + 1];
    float4* dst = (float4*)(ldsF + s * FSTR + r * 8);
    dst[0] = v0;
    dst[1] = v1;
  }
  if (tid < 96) {
    int dd = tid >> 5, s = tid & 31;
    int nn = sIdx[s];
    ldsX[dd * NS + s] = xyz[((size_t)b * NN_ + nn) * 3 + dd] -
                        new_xyz[(size_t)q * 3 + dd];
  }
  __syncthreads();

  // Write 67 rows of 32 floats (128B coalesced per row), 8 rows at a time.
  const int s = tid & 31;
  const int r0 = tid >> 5;
#pragma unroll
  for (int k = 0; k < 9; k++) {
    int row = r0 + k * 8;
    if (row < 67) {
      float v = (row < 3) ? ldsX[row * NS + s] : ldsF[s * FSTR + (row - 3)];
      out[(((size_t)b * 67 + row) * NPOINT + p) * NS + s] = v;
    }
  }
}

extern "C" void kernel_launch(void* const* d_in, const int* in_sizes, int n_in,
                              void* d_out, int out_size, void* d_ws, size_t ws_size,
                              hipStream_t stream) {
  const float* xyz      = (const float*)d_in[0];   // (4,8192,3)
  const float* new_xyz  = (const float*)d_in[1];   // (4,2048,3)
  // d_in[2], d_in[3]: components — unused (LAMBDA=0.5 makes mask a no-op)
  const float* features = (const float*)d_in[4];   // (4,64,8192)
  float* out = (float*)d_out;

  // workspace layout: [idx: 4*2048*32 int = 1MB][featsT: 4*8192*64 f32 = 8MB]
  int* idxArr = (int*)d_ws;
  float* featsT = (float*)((char*)d_ws + (size_t)BQ * NPOINT * NS * sizeof(int));

  knn_kernel<<<BQ * NPOINT, T1, 0, stream>>>(xyz, new_xyz, idxArr);
  transpose_kernel<<<dim3(NN_ / 32, CF / 32, BQ), dim3(32, 8), 0, stream>>>(features, featsT);
  group_kernel<<<BQ * NPOINT, T1, 0, stream>>>(xyz, new_xyz, featsT, idxArr, out);
}

// Round 3
// 147.110 us; speedup vs baseline: 1.1647x; 1.1647x over previous
//
#include <hip/hip_runtime.h>

// GAGKNNQueryAndGroup: B=4, N=8192, NPOINT=2048, C=64, NSAMPLE=32, LAMBDA=0.5
// Inputs: xyz(B,N,3) f32 | new_xyz(B,NPOINT,3) f32 | components(B,N,1) int |
//         new_components(B,NPOINT,1) int | features(B,C,N) f32
// Output: (B, 3+C, NPOINT, NS) f32
//
// NOTE: LAMBDA == 0.5 makes the component mask numerically irrelevant:
// where(mask, d*0.5, d*0.5) == d*0.5 (exact, order-preserving). Components unused.
// Output is indices-gathered data only, so any monotone rescale of distances
// (incl. dropping the *0.5) leaves results bit-identical.

#define BQ 4
#define NN_ 8192
#define NPOINT 2048
#define CF 64
#define NS 32
#define T1 256
#define PER (NN_ / T1)   // 32 points per thread
#define QB 4             // queries per block (R2: amortize point sweep 4x)
#define CAPQ 192         // per-query candidate capacity (expected ~44)
#define M_EPS 1e-3f      // >> worst-case |fma-form - exact| rounding gap (~1e-4)

// ---------------- Phase 1: exact top-32 selection, 4 queries/block ----------------
// Pass 1 computes a cheap fma-form score s = |p|^2 - 2 p.q per (point,query) and
// tracks per-thread minima. theta_k = (32nd-smallest of 64 disjoint group-minima)
// + |q|^2 + M_EPS is a guaranteed upper bound on the true 32nd-smallest EXACT
// distance: the 32 smallest group-minima are 32 distinct real point scores, and
// M_EPS covers the approx-vs-exact rounding gap. Pass 2 prefilters with s
// (second margin), then evaluates the bit-exact reference distance only for
// survivors (~0.6%), storing (d_bits, idx) for an exact stable rank.
__global__ __launch_bounds__(256) void knn_kernel(const float* __restrict__ xyz,
                                                  const float* __restrict__ new_xyz,
                                                  int* __restrict__ idxOut) {
  const int tile = blockIdx.x;                    // 0 .. B*NPOINT/QB-1
  const int b = tile / (NPOINT / QB);
  const int q0 = b * NPOINT + (tile % (NPOINT / QB)) * QB;  // global query base
  const int tid = threadIdx.x;
  const int lane = tid & 63;
  const int wid = tid >> 6;

  float qx[QB], qy[QB], qz[QB], qn[QB];
#pragma unroll
  for (int k = 0; k < QB; k++) {
    qx[k] = new_xyz[(q0 + k) * 3 + 0];
    qy[k] = new_xyz[(q0 + k) * 3 + 1];
    qz[k] = new_xyz[(q0 + k) * 3 + 2];
    qn[k] = qx[k] * qx[k] + qy[k] * qy[k] + qz[k] * qz[k];
  }

  const float* __restrict__ base = xyz + (size_t)b * NN_ * 3;

  // ---- Pass 1: running min of s = |p|^2 - 2 p.q (fast form, fma allowed) ----
  float smin_r[QB];
#pragma unroll
  for (int k = 0; k < QB; k++) smin_r[k] = 3.4e38f;

  for (int j = 0; j < PER; j++) {
    const int n = tid + j * T1;
    const float x = base[n * 3 + 0];
    const float y = base[n * 3 + 1];
    const float z = base[n * 3 + 2];
    const float pp = x * x + y * y + z * z;
#pragma unroll
    for (int k = 0; k < QB; k++) {
      float dot = x * qx[k] + y * qy[k] + z * qz[k];
      float s = pp - 2.0f * dot;
      smin_r[k] = fminf(smin_r[k], s);
    }
  }

  __shared__ float sMin[QB][T1];
  __shared__ float sTheta[QB];
  __shared__ unsigned long long cand[QB][CAPQ];
  __shared__ int cnt[QB];
#pragma unroll
  for (int k = 0; k < QB; k++) sMin[k][tid] = smin_r[k];
  if (tid < QB) cnt[tid] = 0;
  __syncthreads();

  // ---- theta: wave w handles query w ----
  {
    const int k = wid;
    float m = fminf(fminf(sMin[k][lane], sMin[k][lane + 64]),
                    fminf(sMin[k][lane + 128], sMin[k][lane + 192]));
    // 64-lane in-register bitonic sort, ascending
#pragma unroll
    for (int kk = 2; kk <= 64; kk <<= 1) {
#pragma unroll
      for (int jj = kk >> 1; jj > 0; jj >>= 1) {
        float o = __shfl_xor(m, jj);
        bool up = ((lane & kk) == 0);
        bool lower = ((lane & jj) == 0);
        m = (up == lower) ? fminf(m, o) : fmaxf(m, o);
      }
    }
    if (lane == 31) sTheta[k] = m + qn[k] + M_EPS;   // d-space upper bound
  }
  __syncthreads();

  float thd[QB];
#pragma unroll
  for (int k = 0; k < QB; k++) thd[k] = sTheta[k];

  // ---- Pass 2: prefilter (fast form), exact distance for survivors ----
  for (int j = 0; j < PER; j++) {
    const int n = tid + j * T1;
    const float x = base[n * 3 + 0];
    const float y = base[n * 3 + 1];
    const float z = base[n * 3 + 2];
    const float pp = x * x + y * y + z * z;
#pragma unroll
    for (int k = 0; k < QB; k++) {
      float dot = x * qx[k] + y * qy[k] + z * qz[k];
      float s = pp - 2.0f * dot + qn[k];
      if (s <= thd[k] + M_EPS) {
        // bit-exact reference distance: no FMA contraction, left-to-right sum
        float dx = x - qx[k], dy = y - qy[k], dz = z - qz[k];
        float d = __fadd_rn(__fadd_rn(__fmul_rn(dx, dx), __fmul_rn(dy, dy)),
                            __fmul_rn(dz, dz));
        if (d <= thd[k]) {
          int pos = atomicAdd(&cnt[k], 1);
          if (pos < CAPQ)
            cand[k][pos] =
                ((unsigned long long)__float_as_uint(d) << 32) | (unsigned)n;
        }
      }
    }
  }
  __syncthreads();

  // ---- exact stable rank by (dist_bits, idx): wave w ranks query w ----
  {
    const int k = wid;
    const int m = cnt[k] < CAPQ ? cnt[k] : CAPQ;
    for (int i = lane; i < m; i += 64) {
      unsigned long long x = cand[k][i];
      int r = 0;
      for (int j = 0; j < m; j++) r += (cand[k][j] < x) ? 1 : 0;
      if (r < NS) idxOut[(q0 + k) * NS + r] = (int)(x & 0xffffffffu);
    }
  }
}

// ---------------- Phase 2: features (B,C,N) -> featsT (B,N,C) ----------------
__global__ __launch_bounds__(256) void transpose_kernel(const float* __restrict__ f,
                                                        float* __restrict__ ft) {
  __shared__ float t[32][33];
  const int b = blockIdx.z;
  const int n0 = blockIdx.x * 32;
  const int c0 = blockIdx.y * 32;
  const int tx = threadIdx.x;   // 0..31
  const int ty = threadIdx.y;   // 0..7
#pragma unroll
  for (int i = 0; i < 4; i++) {
    int c = c0 + ty + i * 8;
    t[ty + i * 8][tx] = f[(size_t)b * CF * NN_ + (size_t)c * NN_ + n0 + tx];
  }
  __syncthreads();
#pragma unroll
  for (int i = 0; i < 4; i++) {
    int nrow = n0 + ty + i * 8;
    ft[(size_t)b * NN_ * CF + (size_t)nrow * CF + c0 + tx] = t[tx][ty + i * 8];
  }
}

// ---------------- Phase 3: gather + grouped write ----------------
#define FSTR 68   // LDS row stride: multiple of 4 (float4 stores), 4-way bank alias only
__global__ __launch_bounds__(256) void group_kernel(const float* __restrict__ xyz,
                                                    const float* __restrict__ new_xyz,
                                                    const float* __restrict__ featsT,
                                                    const int* __restrict__ idxArr,
                                                    float* __restrict__ out) {
  const int q = blockIdx.x;            // b*NPOINT + p
  const int b = q / NPOINT;
  const int p = q - b * NPOINT;
  const int tid = threadIdx.x;

  __shared__ int sIdx[NS];
  __shared__ __align__(16) float ldsF[NS * FSTR];
  __shared__ float ldsX[3 * NS];

  if (tid < NS) sIdx[tid] = idxArr[q * NS + tid];
  __syncthreads();

  {
    // 256 threads = 32 samples x 8 readers; each reader pulls 32B of the
    // 256B contiguous feature row for its sample.
    int s = tid >> 3, r = tid & 7;
    int nn = sIdx[s];
    const float4* src = (const float4*)(featsT + ((size_t)b * NN_ + nn) * CF);
    float4 v0 = src[r * 2];
    float4 v1 = src[r * 2 + 1];
    float4* dst = (float4*)(ldsF + s * FSTR + r * 8);
    dst[0] = v0;
    dst[1] = v1;
  }
  if (tid < 96) {
    int dd = tid >> 5, s = tid & 31;
    int nn = sIdx[s];
    ldsX[dd * NS + s] = xyz[((size_t)b * NN_ + nn) * 3 + dd] -
                        new_xyz[(size_t)q * 3 + dd];
  }
  __syncthreads();

  // Write 67 rows of 32 floats (128B coalesced per row), 8 rows at a time.
  const int s = tid & 31;
  const int r0 = tid >> 5;
#pragma unroll
  for (int k = 0; k < 9; k++) {
    int row = r0 + k * 8;
    if (row < 67) {
      float v = (row < 3) ? ldsX[row * NS + s] : ldsF[s * FSTR + (row - 3)];
      out[(((size_t)b * 67 + row) * NPOINT + p) * NS + s] = v;
    }
  }
}

extern "C" void kernel_launch(void* const* d_in, const int* in_sizes, int n_in,
                              void* d_out, int out_size, void* d_ws, size_t ws_size,
                              hipStream_t stream) {
  const float* xyz      = (const float*)d_in[0];   // (4,8192,3)
  const float* new_xyz  = (const float*)d_in[1];   // (4,2048,3)
  // d_in[2], d_in[3]: components — unused (LAMBDA=0.5 makes mask a no-op)
  const float* features = (const float*)d_in[4];   // (4,64,8192)
  float* out = (float*)d_out;

  // workspace layout: [idx: 4*2048*32 int = 1MB][featsT: 4*8192*64 f32 = 8MB]
  int* idxArr = (int*)d_ws;
  float* featsT = (float*)((char*)d_ws + (size_t)BQ * NPOINT * NS * sizeof(int));

  knn_kernel<<<BQ * NPOINT / QB, T1, 0, stream>>>(xyz, new_xyz, idxArr);
  transpose_kernel<<<dim3(NN_ / 32, CF / 32, BQ), dim3(32, 8), 0, stream>>>(features, featsT);
  group_kernel<<<BQ * NPOINT, T1, 0, stream>>>(xyz, new_xyz, featsT, idxArr, out);
}

// Round 4
// 134.862 us; speedup vs baseline: 1.2705x; 1.0908x over previous
//
#include <hip/hip_runtime.h>

// GAGKNNQueryAndGroup: B=4, N=8192, NPOINT=2048, C=64, NSAMPLE=32, LAMBDA=0.5
// Inputs: xyz(B,N,3) f32 | new_xyz(B,NPOINT,3) f32 | components(B,N,1) int |
//         new_components(B,NPOINT,1) int | features(B,C,N) f32
// Output: (B, 3+C, NPOINT, NS) f32
//
// NOTE: LAMBDA == 0.5 makes the component mask numerically irrelevant:
// where(mask, d*0.5, d*0.5) == d*0.5 (exact, order-preserving). Components unused.
// Output is indices-gathered data only, so any monotone rescale of distances
// (incl. dropping the *0.5) leaves results bit-identical.

#define BQ 4
#define NN_ 8192
#define NPOINT 2048
#define CF 64
#define NS 32
#define T1 256
#define PER (NN_ / T1)   // 32 points per thread
#define QB 4             // queries per block
#define CAPQ 192         // per-query candidate capacity (expected ~44)
#define M_EPS 1e-3f      // >> worst-case |fma-form - exact| rounding gap (~1e-4)

#define KNN_BLOCKS (BQ * NPOINT / QB)            // 2048
#define TR_BLOCKS  ((NN_ / 32) * (CF / 32) * BQ) // 2048

// ---- Fused kernel: blocks [0,KNN_BLOCKS) do knn; rest do the transpose ----
// The two phases touch disjoint data, so grid-partitioned fusion is safe and
// lets the transpose run in the knn phase's occupancy shadow/tail.
__global__ __launch_bounds__(256) void knn_tr_kernel(
    const float* __restrict__ xyz, const float* __restrict__ new_xyz,
    const float* __restrict__ features, int* __restrict__ idxOut,
    float* __restrict__ featsT) {
  const int tid = threadIdx.x;

  if (blockIdx.x >= KNN_BLOCKS) {
    // ---------------- transpose path: features (B,C,N) -> (B,N,C) ----------
    const int t = blockIdx.x - KNN_BLOCKS;
    const int n0 = (t & 255) * 32;
    const int c0 = ((t >> 8) & 1) * 32;
    const int b = t >> 9;
    const int tx = tid & 31;
    const int ty = tid >> 5;   // 0..7
    __shared__ float tr[32][33];
#pragma unroll
    for (int i = 0; i < 4; i++) {
      int c = c0 + ty + i * 8;
      tr[ty + i * 8][tx] = features[(size_t)b * CF * NN_ + (size_t)c * NN_ + n0 + tx];
    }
    __syncthreads();
#pragma unroll
    for (int i = 0; i < 4; i++) {
      int nrow = n0 + ty + i * 8;
      featsT[(size_t)b * NN_ * CF + (size_t)nrow * CF + c0 + tx] = tr[tx][ty + i * 8];
    }
    return;
  }

  // ---------------- knn path: exact top-32, 4 queries/block ----------------
  // Pass 1: cheap fma-form score s = |p|^2 - 2 p.q; theta = (32nd-smallest of
  // 64 disjoint group-minima) + |q|^2 + M_EPS is a guaranteed upper bound on
  // the true 32nd-smallest EXACT distance. Pass 2 prefilters with s, computes
  // the bit-exact reference distance for survivors, exact stable rank at end.
  const int tile = blockIdx.x;
  const int b = tile / (NPOINT / QB);
  const int q0 = b * NPOINT + (tile % (NPOINT / QB)) * QB;
  const int lane = tid & 63;
  const int wid = tid >> 6;

  float qx[QB], qy[QB], qz[QB], qn[QB];
#pragma unroll
  for (int k = 0; k < QB; k++) {
    qx[k] = new_xyz[(q0 + k) * 3 + 0];
    qy[k] = new_xyz[(q0 + k) * 3 + 1];
    qz[k] = new_xyz[(q0 + k) * 3 + 2];
    qn[k] = qx[k] * qx[k] + qy[k] * qy[k] + qz[k] * qz[k];
  }

  // 4 consecutive points per thread per group: 48B = 3 aligned float4 loads.
  const float4* __restrict__ base4 =
      (const float4*)(xyz + (size_t)b * NN_ * 3);

  float smin_r[QB];
#pragma unroll
  for (int k = 0; k < QB; k++) smin_r[k] = 3.4e38f;

#pragma unroll
  for (int g = 0; g < PER / 4; g++) {          // 8 groups x 4 points
    const int v = g * 768 + tid * 3;           // float4 index of group base
    float4 v0 = base4[v + 0];                  // x0 y0 z0 x1
    float4 v1 = base4[v + 1];                  // y1 z1 x2 y2
    float4 v2 = base4[v + 2];                  // z2 x3 y3 z3
    float xs[4] = {v0.x, v0.w, v1.z, v2.y};
    float ys[4] = {v0.y, v1.x, v1.w, v2.z};
    float zs[4] = {v0.z, v1.y, v2.x, v2.w};
#pragma unroll
    for (int i = 0; i < 4; i++) {
      float pp = xs[i] * xs[i] + ys[i] * ys[i] + zs[i] * zs[i];
#pragma unroll
      for (int k = 0; k < QB; k++) {
        float dot = xs[i] * qx[k] + ys[i] * qy[k] + zs[i] * qz[k];
        smin_r[k] = fminf(smin_r[k], pp - 2.0f * dot);
      }
    }
  }

  __shared__ float sMin[QB][T1];
  __shared__ float sTheta[QB];
  __shared__ unsigned long long cand[QB][CAPQ];
  __shared__ int cnt[QB];
#pragma unroll
  for (int k = 0; k < QB; k++) sMin[k][tid] = smin_r[k];
  if (tid < QB) cnt[tid] = 0;
  __syncthreads();

  // theta: wave w handles query w (64-lane in-register bitonic, ascending)
  {
    const int k = wid;
    float m = fminf(fminf(sMin[k][lane], sMin[k][lane + 64]),
                    fminf(sMin[k][lane + 128], sMin[k][lane + 192]));
#pragma unroll
    for (int kk = 2; kk <= 64; kk <<= 1) {
#pragma unroll
      for (int jj = kk >> 1; jj > 0; jj >>= 1) {
        float o = __shfl_xor(m, jj);
        bool up = ((lane & kk) == 0);
        bool lower = ((lane & jj) == 0);
        m = (up == lower) ? fminf(m, o) : fmaxf(m, o);
      }
    }
    if (lane == 31) sTheta[k] = m + qn[k] + M_EPS;   // d-space upper bound
  }
  __syncthreads();

  float thd[QB];
#pragma unroll
  for (int k = 0; k < QB; k++) thd[k] = sTheta[k];

  // Pass 2: prefilter (fast form), bit-exact distance for survivors (~0.6%).
#pragma unroll
  for (int g = 0; g < PER / 4; g++) {
    const int v = g * 768 + tid * 3;
    float4 v0 = base4[v + 0];
    float4 v1 = base4[v + 1];
    float4 v2 = base4[v + 2];
    float xs[4] = {v0.x, v0.w, v1.z, v2.y};
    float ys[4] = {v0.y, v1.x, v1.w, v2.z};
    float zs[4] = {v0.z, v1.y, v2.x, v2.w};
#pragma unroll
    for (int i = 0; i < 4; i++) {
      float pp = xs[i] * xs[i] + ys[i] * ys[i] + zs[i] * zs[i];
#pragma unroll
      for (int k = 0; k < QB; k++) {
        float dot = xs[i] * qx[k] + ys[i] * qy[k] + zs[i] * qz[k];
        float s = pp - 2.0f * dot + qn[k];
        if (s <= thd[k] + M_EPS) {
          // bit-exact reference distance: no FMA, left-to-right sum
          float dx = xs[i] - qx[k], dy = ys[i] - qy[k], dz = zs[i] - qz[k];
          float d = __fadd_rn(__fadd_rn(__fmul_rn(dx, dx), __fmul_rn(dy, dy)),
                              __fmul_rn(dz, dz));
          if (d <= thd[k]) {
            int n = g * 1024 + tid * 4 + i;
            int pos = atomicAdd(&cnt[k], 1);
            if (pos < CAPQ)
              cand[k][pos] =
                  ((unsigned long long)__float_as_uint(d) << 32) | (unsigned)n;
          }
        }
      }
    }
  }
  __syncthreads();

  // exact stable rank by (dist_bits, idx): wave w ranks query w
  {
    const int k = wid;
    const int m = cnt[k] < CAPQ ? cnt[k] : CAPQ;
    for (int i = lane; i < m; i += 64) {
      unsigned long long x = cand[k][i];
      int r = 0;
      for (int j = 0; j < m; j++) r += (cand[k][j] < x) ? 1 : 0;
      if (r < NS) idxOut[(q0 + k) * NS + r] = (int)(x & 0xffffffffu);
    }
  }
}

// ---------------- Phase 2: gather + grouped write ----------------
#define FSTR 68   // LDS row stride: multiple of 4 (float4 stores), 4-way bank alias only
__global__ __launch_bounds__(256) void group_kernel(const float* __restrict__ xyz,
                                                    const float* __restrict__ new_xyz,
                                                    const float* __restrict__ featsT,
                                                    const int* __restrict__ idxArr,
                                                    float* __restrict__ out) {
  const int q = blockIdx.x;            // b*NPOINT + p
  const int b = q / NPOINT;
  const int p = q - b * NPOINT;
  const int tid = threadIdx.x;

  __shared__ int sIdx[NS];
  __shared__ __align__(16) float ldsF[NS * FSTR];
  __shared__ float ldsX[3 * NS];

  if (tid < NS) sIdx[tid] = idxArr[q * NS + tid];
  __syncthreads();

  {
    // 256 threads = 32 samples x 8 readers; each reader pulls 32B of the
    // 256B contiguous feature row for its sample.
    int s = tid >> 3, r = tid & 7;
    int nn = sIdx[s];
    const float4* src = (const float4*)(featsT + ((size_t)b * NN_ + nn) * CF);
    float4 v0 = src[r * 2];
    float4 v1 = src[r * 2 + 1];
    float4* dst = (float4*)(ldsF + s * FSTR + r * 8);
    dst[0] = v0;
    dst[1] = v1;
  }
  if (tid < 96) {
    int dd = tid >> 5, s = tid & 31;
    int nn = sIdx[s];
    ldsX[dd * NS + s] = xyz[((size_t)b * NN_ + nn) * 3 + dd] -
                        new_xyz[(size_t)q * 3 + dd];
  }
  __syncthreads();

  // Write 67 rows of 32 floats (128B coalesced per row), 8 rows at a time.
  const int s = tid & 31;
  const int r0 = tid >> 5;
#pragma unroll
  for (int k = 0; k < 9; k++) {
    int row = r0 + k * 8;
    if (row < 67) {
      float v = (row < 3) ? ldsX[row * NS + s] : ldsF[s * FSTR + (row - 3)];
      out[(((size_t)b * 67 + row) * NPOINT + p) * NS + s] = v;
    }
  }
}

extern "C" void kernel_launch(void* const* d_in, const int* in_sizes, int n_in,
                              void* d_out, int out_size, void* d_ws, size_t ws_size,
                              hipStream_t stream) {
  const float* xyz      = (const float*)d_in[0];   // (4,8192,3)
  const float* new_xyz  = (const float*)d_in[1];   // (4,2048,3)
  // d_in[2], d_in[3]: components — unused (LAMBDA=0.5 makes mask a no-op)
  const float* features = (const float*)d_in[4];   // (4,64,8192)
  float* out = (float*)d_out;

  // workspace layout: [idx: 4*2048*32 int = 1MB][featsT: 4*8192*64 f32 = 8MB]
  int* idxArr = (int*)d_ws;
  float* featsT = (float*)((char*)d_ws + (size_t)BQ * NPOINT * NS * sizeof(int));

  knn_tr_kernel<<<KNN_BLOCKS + TR_BLOCKS, T1, 0, stream>>>(xyz, new_xyz, features,
                                                           idxArr, featsT);
  group_kernel<<<BQ * NPOINT, T1, 0, stream>>>(xyz, new_xyz, featsT, idxArr, out);
}

// Round 5
// 134.040 us; speedup vs baseline: 1.2783x; 1.0061x over previous
//
#include <hip/hip_runtime.h>

// GAGKNNQueryAndGroup: B=4, N=8192, NPOINT=2048, C=64, NSAMPLE=32, LAMBDA=0.5
// Output: (B, 3+C, NPOINT, NS) f32
//
// LAMBDA == 0.5 makes the component mask numerically irrelevant (d*0.5 both
// branches, order-preserving) -> components unused. Output is gathered data
// only, so monotone distance rescales leave results bit-identical.

#define BQ 4
#define NN_ 8192
#define NPOINT 2048
#define CF 64
#define NS 32
#define T1 256
#define PER (NN_ / T1)   // 32 points per thread
#define QB 8             // queries per block (R5: halves xyz sweep traffic)
#define CAPQ 192         // per-query candidate capacity (expected ~44)
#define M_EPS 1e-3f      // >> |fma-form - exact| rounding gap (~1e-5)

#define KNN_BLOCKS (BQ * NPOINT / QB)            // 1024
#define TR_BLOCKS  ((NN_ / 32) * (CF / 32) * BQ) // 2048

// LDS arena: knn path needs QB*T1*4 (sMin) + QB*CAPQ*8 (cand) + QB*4 (theta)
// + QB*4 (cnt) = 20544B; transpose path needs 32*33*4 = 4224B. Overlaid.
#define SMEM_BYTES (QB * T1 * 4 + QB * CAPQ * 8 + QB * 4 + QB * 4)

__device__ __forceinline__ float rfl(float x) {
  return __int_as_float(__builtin_amdgcn_readfirstlane(__float_as_int(x)));
}

__global__ __launch_bounds__(256) void knn_tr_kernel(
    const float* __restrict__ xyz, const float* __restrict__ new_xyz,
    const float* __restrict__ features, int* __restrict__ idxOut,
    float* __restrict__ featsT) {
  __shared__ __align__(16) char smem[SMEM_BYTES];
  const int tid = threadIdx.x;

  if (blockIdx.x >= KNN_BLOCKS) {
    // ---------------- transpose path: features (B,C,N) -> (B,N,C) ----------
    float(*tr)[33] = (float(*)[33])smem;
    const int t = blockIdx.x - KNN_BLOCKS;
    const int n0 = (t & 255) * 32;
    const int c0 = ((t >> 8) & 1) * 32;
    const int b = t >> 9;
    const int tx = tid & 31;
    const int ty = tid >> 5;   // 0..7
#pragma unroll
    for (int i = 0; i < 4; i++) {
      int c = c0 + ty + i * 8;
      tr[ty + i * 8][tx] = features[(size_t)b * CF * NN_ + (size_t)c * NN_ + n0 + tx];
    }
    __syncthreads();
#pragma unroll
    for (int i = 0; i < 4; i++) {
      int nrow = n0 + ty + i * 8;
      featsT[(size_t)b * NN_ * CF + (size_t)nrow * CF + c0 + tx] = tr[tx][ty + i * 8];
    }
    return;
  }

  // ---------------- knn path: exact top-32, 8 queries/block ----------------
  // Pass 1: fma-form score t = pp - 2 p.q via 3 fmas (qx2 = -2 qx in SGPR).
  // theta_k = (32nd-smallest of 64 disjoint 128-point group minima) + |q|^2
  // + M_EPS: guaranteed upper bound on the true 32nd-smallest EXACT distance.
  // Pass 2 prefilters with t <= th2 (second margin), recomputes the bit-exact
  // reference distance for rare survivors, then exact stable (d_bits,idx) rank.
  float(*sMin)[T1] = (float(*)[T1])smem;
  unsigned long long(*cand)[CAPQ] =
      (unsigned long long(*)[CAPQ])(smem + QB * T1 * 4);
  float* sTheta = (float*)(smem + QB * T1 * 4 + QB * CAPQ * 8);
  int* cnt = (int*)(smem + QB * T1 * 4 + QB * CAPQ * 8 + QB * 4);

  const int tile = blockIdx.x;
  const int b = tile / (NPOINT / QB);
  const int q0 = b * NPOINT + (tile % (NPOINT / QB)) * QB;
  const int lane = tid & 63;
  const int wid = tid >> 6;

  // Block-uniform query constants -> SGPRs (readfirstlane). -2*q and -0.5*(-2q)
  // are exact power-of-two scalings, so the exact path below is bit-identical.
  float qx2[QB], qy2[QB], qz2[QB], qnn[QB];
#pragma unroll
  for (int k = 0; k < QB; k++) {
    float ax = new_xyz[(q0 + k) * 3 + 0];
    float ay = new_xyz[(q0 + k) * 3 + 1];
    float az = new_xyz[(q0 + k) * 3 + 2];
    qx2[k] = rfl(-2.0f * ax);
    qy2[k] = rfl(-2.0f * ay);
    qz2[k] = rfl(-2.0f * az);
    qnn[k] = rfl(ax * ax + ay * ay + az * az);
  }

  const float4* __restrict__ base4 = (const float4*)(xyz + (size_t)b * NN_ * 3);

  float smin_r[QB];
#pragma unroll
  for (int k = 0; k < QB; k++) smin_r[k] = 3.4e38f;

#pragma unroll
  for (int g = 0; g < PER / 4; g++) {          // 8 groups x 4 consecutive points
    const int v = g * 768 + tid * 3;           // float4 index of 48B group
    float4 v0 = base4[v + 0];                  // x0 y0 z0 x1
    float4 v1 = base4[v + 1];                  // y1 z1 x2 y2
    float4 v2 = base4[v + 2];                  // z2 x3 y3 z3
    float xs[4] = {v0.x, v0.w, v1.z, v2.y};
    float ys[4] = {v0.y, v1.x, v1.w, v2.z};
    float zs[4] = {v0.z, v1.y, v2.x, v2.w};
#pragma unroll
    for (int i = 0; i < 4; i++) {
      float pp = fmaf(zs[i], zs[i], fmaf(ys[i], ys[i], xs[i] * xs[i]));
#pragma unroll
      for (int k = 0; k < QB; k++) {
        float t = fmaf(xs[i], qx2[k], pp);
        t = fmaf(ys[i], qy2[k], t);
        t = fmaf(zs[i], qz2[k], t);
        smin_r[k] = fminf(smin_r[k], t);
      }
    }
  }

#pragma unroll
  for (int k = 0; k < QB; k++) sMin[k][tid] = smin_r[k];
  if (tid < QB) cnt[tid] = 0;
  __syncthreads();

  // theta: wave w handles queries 2w, 2w+1 (64-lane register bitonic each)
#pragma unroll
  for (int t2 = 0; t2 < 2; t2++) {
    const int k = wid * 2 + t2;
    float m = fminf(fminf(sMin[k][lane], sMin[k][lane + 64]),
                    fminf(sMin[k][lane + 128], sMin[k][lane + 192]));
#pragma unroll
    for (int kk = 2; kk <= 64; kk <<= 1) {
#pragma unroll
      for (int jj = kk >> 1; jj > 0; jj >>= 1) {
        float o = __shfl_xor(m, jj);
        bool up = ((lane & kk) == 0);
        bool lower = ((lane & jj) == 0);
        m = (up == lower) ? fminf(m, o) : fmaxf(m, o);
      }
    }
    if (lane == 31) sTheta[k] = m + qnn[k] + M_EPS;   // d-space upper bound
  }
  __syncthreads();

  float thd[QB], th2[QB];
#pragma unroll
  for (int k = 0; k < QB; k++) {
    thd[k] = rfl(sTheta[k]);                      // exact-accept bound (d-space)
    th2[k] = rfl(thd[k] + M_EPS - qnn[k]);        // prefilter bound (t-space)
  }

  // Pass 2: prefilter (3 fmas + cmp), bit-exact distance for rare survivors.
#pragma unroll
  for (int g = 0; g < PER / 4; g++) {
    const int v = g * 768 + tid * 3;
    float4 v0 = base4[v + 0];
    float4 v1 = base4[v + 1];
    float4 v2 = base4[v + 2];
    float xs[4] = {v0.x, v0.w, v1.z, v2.y};
    float ys[4] = {v0.y, v1.x, v1.w, v2.z};
    float zs[4] = {v0.z, v1.y, v2.x, v2.w};
#pragma unroll
    for (int i = 0; i < 4; i++) {
      float pp = fmaf(zs[i], zs[i], fmaf(ys[i], ys[i], xs[i] * xs[i]));
#pragma unroll
      for (int k = 0; k < QB; k++) {
        float t = fmaf(xs[i], qx2[k], pp);
        t = fmaf(ys[i], qy2[k], t);
        t = fmaf(zs[i], qz2[k], t);
        if (t <= th2[k]) {
          // exact query coords: -0.5f*qx2 == qx bit-exactly (pow2 scalings)
          float dx = xs[i] - (-0.5f * qx2[k]);
          float dy = ys[i] - (-0.5f * qy2[k]);
          float dz = zs[i] - (-0.5f * qz2[k]);
          // bit-exact reference distance: no FMA, left-to-right sum
          float d = __fadd_rn(__fadd_rn(__fmul_rn(dx, dx), __fmul_rn(dy, dy)),
                              __fmul_rn(dz, dz));
          if (d <= thd[k]) {
            int n = g * 1024 + tid * 4 + i;
            int pos = atomicAdd(&cnt[k], 1);
            if (pos < CAPQ)
              cand[k][pos] =
                  ((unsigned long long)__float_as_uint(d) << 32) | (unsigned)n;
          }
        }
      }
    }
  }
  __syncthreads();

  // exact stable rank by (dist_bits, idx): wave w ranks queries 2w, 2w+1
#pragma unroll
  for (int t2 = 0; t2 < 2; t2++) {
    const int k = wid * 2 + t2;
    const int m = cnt[k] < CAPQ ? cnt[k] : CAPQ;
    for (int i = lane; i < m; i += 64) {
      unsigned long long x = cand[k][i];
      int r = 0;
      for (int j = 0; j < m; j++) r += (cand[k][j] < x) ? 1 : 0;
      if (r < NS) idxOut[(q0 + k) * NS + r] = (int)(x & 0xffffffffu);
    }
  }
}

// ---------------- Phase 2: gather + grouped write ----------------
#define FSTR 68   // LDS row stride: multiple of 4 (float4 stores), 4-way bank alias only
__global__ __launch_bounds__(256) void group_kernel(const float* __restrict__ xyz,
                                                    const float* __restrict__ new_xyz,
                                                    const float* __restrict__ featsT,
                                                    const int* __restrict__ idxArr,
                                                    float* __restrict__ out) {
  const int q = blockIdx.x;            // b*NPOINT + p
  const int b = q / NPOINT;
  const int p = q - b * NPOINT;
  const int tid = threadIdx.x;

  __shared__ int sIdx[NS];
  __shared__ __align__(16) float ldsF[NS * FSTR];
  __shared__ float ldsX[3 * NS];

  if (tid < NS) sIdx[tid] = idxArr[q * NS + tid];
  __syncthreads();

  {
    // 256 threads = 32 samples x 8 readers; each reader pulls 32B of the
    // 256B contiguous feature row for its sample.
    int s = tid >> 3, r = tid & 7;
    int nn = sIdx[s];
    const float4* src = (const float4*)(featsT + ((size_t)b * NN_ + nn) * CF);
    float4 v0 = src[r * 2];
    float4 v1 = src[r * 2 + 1];
    float4* dst = (float4*)(ldsF + s * FSTR + r * 8);
    dst[0] = v0;
    dst[1] = v1;
  }
  if (tid < 96) {
    int dd = tid >> 5, s = tid & 31;
    int nn = sIdx[s];
    ldsX[dd * NS + s] = xyz[((size_t)b * NN_ + nn) * 3 + dd] -
                        new_xyz[(size_t)q * 3 + dd];
  }
  __syncthreads();

  // Write 67 rows of 32 floats (128B coalesced per row), 8 rows at a time.
  const int s = tid & 31;
  const int r0 = tid >> 5;
#pragma unroll
  for (int k = 0; k < 9; k++) {
    int row = r0 + k * 8;
    if (row < 67) {
      float v = (row < 3) ? ldsX[row * NS + s] : ldsF[s * FSTR + (row - 3)];
      out[(((size_t)b * 67 + row) * NPOINT + p) * NS + s] = v;
    }
  }
}

extern "C" void kernel_launch(void* const* d_in, const int* in_sizes, int n_in,
                              void* d_out, int out_size, void* d_ws, size_t ws_size,
                              hipStream_t stream) {
  const float* xyz      = (const float*)d_in[0];   // (4,8192,3)
  const float* new_xyz  = (const float*)d_in[1];   // (4,2048,3)
  // d_in[2], d_in[3]: components — unused (LAMBDA=0.5 makes mask a no-op)
  const float* features = (const float*)d_in[4];   // (4,64,8192)
  float* out = (float*)d_out;

  // workspace layout: [idx: 4*2048*32 int = 1MB][featsT: 4*8192*64 f32 = 8MB]
  int* idxArr = (int*)d_ws;
  float* featsT = (float*)((char*)d_ws + (size_t)BQ * NPOINT * NS * sizeof(int));

  knn_tr_kernel<<<KNN_BLOCKS + TR_BLOCKS, T1, 0, stream>>>(xyz, new_xyz, features,
                                                           idxArr, featsT);
  group_kernel<<<BQ * NPOINT, T1, 0, stream>>>(xyz, new_xyz, featsT, idxArr, out);
}

// Round 6
// 129.077 us; speedup vs baseline: 1.3275x; 1.0385x over previous
//
#include <hip/hip_runtime.h>

// GAGKNNQueryAndGroup: B=4, N=8192, NPOINT=2048, C=64, NSAMPLE=32, LAMBDA=0.5
// Output: (B, 3+C, NPOINT, NS) f32
//
// LAMBDA == 0.5 makes the component mask numerically irrelevant (d*0.5 both
// branches, order-preserving) -> components unused. Output is gathered data
// only, so monotone distance rescales leave results bit-identical.

#define BQ 4
#define NN_ 8192
#define NPOINT 2048
#define CF 64
#define NS 32
#define T1 256
#define PER (NN_ / T1)   // 32 points per thread
#define QB 8             // queries per block
#define CAPQ 128         // per-query candidate capacity (expected ~44)
#define M_EPS 1e-3f      // >> |fma-form - exact| rounding gap (~1e-5)

#define KNN_BLOCKS (BQ * NPOINT / QB)            // 1024
#define TR_BLOCKS  ((NN_ / 32) * (CF / 32) * BQ) // 2048

// LDS arena (12,416B -> 8 blocks/CU, thread-capped, 100% wave ceiling):
//  region A (8192B): sMin[QB][T1] (pass1) / keys[QB][CAPQ] u64 (rank) /
//                    tr[32][33] (transpose path) -- phases disjoint.
//  region B (4096B): candI[QB][CAPQ] u32 (candidate indices)
//  region C (64B):   sTheta[QB] + cnt[QB]
#define REG_A (QB * T1 * 4)
#define REG_B (QB * CAPQ * 4)
#define SMEM_BYTES (REG_A + REG_B + QB * 4 + QB * 4)

__device__ __forceinline__ float rfl(float x) {
  return __int_as_float(__builtin_amdgcn_readfirstlane(__float_as_int(x)));
}

__global__ __launch_bounds__(256) void knn_tr_kernel(
    const float* __restrict__ xyz, const float* __restrict__ new_xyz,
    const float* __restrict__ features, int* __restrict__ idxOut,
    float* __restrict__ featsT) {
  __shared__ __align__(16) char smem[SMEM_BYTES];
  const int tid = threadIdx.x;

  if (blockIdx.x >= KNN_BLOCKS) {
    // ---------------- transpose path: features (B,C,N) -> (B,N,C) ----------
    float(*tr)[33] = (float(*)[33])smem;
    const int t = blockIdx.x - KNN_BLOCKS;
    const int n0 = (t & 255) * 32;
    const int c0 = ((t >> 8) & 1) * 32;
    const int b = t >> 9;
    const int tx = tid & 31;
    const int ty = tid >> 5;   // 0..7
#pragma unroll
    for (int i = 0; i < 4; i++) {
      int c = c0 + ty + i * 8;
      tr[ty + i * 8][tx] = features[(size_t)b * CF * NN_ + (size_t)c * NN_ + n0 + tx];
    }
    __syncthreads();
#pragma unroll
    for (int i = 0; i < 4; i++) {
      int nrow = n0 + ty + i * 8;
      featsT[(size_t)b * NN_ * CF + (size_t)nrow * CF + c0 + tx] = tr[tx][ty + i * 8];
    }
    return;
  }

  // ---------------- knn path: exact top-32, 8 queries/block ----------------
  // Pass 1 (rolled): fma-form score t = pp - 2 p.q (qx2 = -2 qx in SGPR).
  // theta_k = (32nd-smallest of 64 disjoint 128-point group minima) + |q|^2
  // + M_EPS: guaranteed upper bound on the true 32nd-smallest EXACT distance.
  // Pass 2 (rolled, tiny body): push candidate INDEX only for t <= th2.
  // Rank phase: recompute bit-exact reference distance for the ~44 candidates
  // per query, stable rank by (d_bits, idx). Extras with d>theta rank >=32 and
  // fall out naturally. Hot-loop code stays small -> I-cache resident.
  float(*sMin)[T1] = (float(*)[T1])smem;                         // region A
  unsigned long long(*keys)[CAPQ] = (unsigned long long(*)[CAPQ])smem;  // A, after pass1
  unsigned int(*candI)[CAPQ] = (unsigned int(*)[CAPQ])(smem + REG_A);   // region B
  float* sTheta = (float*)(smem + REG_A + REG_B);
  int* cnt = (int*)(smem + REG_A + REG_B + QB * 4);

  const int tile = blockIdx.x;
  const int b = tile / (NPOINT / QB);
  const int q0 = b * NPOINT + (tile % (NPOINT / QB)) * QB;
  const int lane = tid & 63;
  const int wid = tid >> 6;

  // Block-uniform query constants -> SGPRs (readfirstlane).
  float qx2[QB], qy2[QB], qz2[QB], qnn[QB];
#pragma unroll
  for (int k = 0; k < QB; k++) {
    float ax = new_xyz[(q0 + k) * 3 + 0];
    float ay = new_xyz[(q0 + k) * 3 + 1];
    float az = new_xyz[(q0 + k) * 3 + 2];
    qx2[k] = rfl(-2.0f * ax);
    qy2[k] = rfl(-2.0f * ay);
    qz2[k] = rfl(-2.0f * az);
    qnn[k] = rfl(ax * ax + ay * ay + az * az);
  }

  const float4* __restrict__ base4 = (const float4*)(xyz + (size_t)b * NN_ * 3);

  float smin_r[QB];
#pragma unroll
  for (int k = 0; k < QB; k++) smin_r[k] = 3.4e38f;

  // ---- Pass 1 (rolled: keep code small; I-cache was the R4/R5 bottleneck) ----
#pragma unroll 2
  for (int g = 0; g < PER / 4; g++) {          // 8 groups x 4 consecutive points
    const int v = g * 768 + tid * 3;           // float4 index of 48B group
    float4 v0 = base4[v + 0];                  // x0 y0 z0 x1
    float4 v1 = base4[v + 1];                  // y1 z1 x2 y2
    float4 v2 = base4[v + 2];                  // z2 x3 y3 z3
    float xs[4] = {v0.x, v0.w, v1.z, v2.y};
    float ys[4] = {v0.y, v1.x, v1.w, v2.z};
    float zs[4] = {v0.z, v1.y, v2.x, v2.w};
#pragma unroll
    for (int i = 0; i < 4; i++) {
      float pp = fmaf(zs[i], zs[i], fmaf(ys[i], ys[i], xs[i] * xs[i]));
#pragma unroll
      for (int k = 0; k < QB; k++) {
        float t = fmaf(xs[i], qx2[k], pp);
        t = fmaf(ys[i], qy2[k], t);
        t = fmaf(zs[i], qz2[k], t);
        smin_r[k] = fminf(smin_r[k], t);
      }
    }
  }

#pragma unroll
  for (int k = 0; k < QB; k++) sMin[k][tid] = smin_r[k];
  if (tid < QB) cnt[tid] = 0;
  __syncthreads();

  // ---- theta: wave w handles queries 2w,2w+1 (64-lane register bitonic) ----
#pragma unroll
  for (int t2 = 0; t2 < 2; t2++) {
    const int k = wid * 2 + t2;
    float m = fminf(fminf(sMin[k][lane], sMin[k][lane + 64]),
                    fminf(sMin[k][lane + 128], sMin[k][lane + 192]));
#pragma unroll
    for (int kk = 2; kk <= 64; kk <<= 1) {
#pragma unroll
      for (int jj = kk >> 1; jj > 0; jj >>= 1) {
        float o = __shfl_xor(m, jj);
        bool up = ((lane & kk) == 0);
        bool lower = ((lane & jj) == 0);
        m = (up == lower) ? fminf(m, o) : fmaxf(m, o);
      }
    }
    if (lane == 31) sTheta[k] = m + qnn[k] + M_EPS;   // d-space upper bound
  }
  __syncthreads();

  float th2[QB];
#pragma unroll
  for (int k = 0; k < QB; k++)
    th2[k] = rfl(sTheta[k] + M_EPS - qnn[k]);   // prefilter bound (t-space)

  // ---- Pass 2 (rolled, tiny rare-path: push index only) ----
#pragma unroll 1
  for (int g = 0; g < PER / 4; g++) {
    const int v = g * 768 + tid * 3;
    float4 v0 = base4[v + 0];
    float4 v1 = base4[v + 1];
    float4 v2 = base4[v + 2];
    float xs[4] = {v0.x, v0.w, v1.z, v2.y};
    float ys[4] = {v0.y, v1.x, v1.w, v2.z};
    float zs[4] = {v0.z, v1.y, v2.x, v2.w};
#pragma unroll
    for (int i = 0; i < 4; i++) {
      float pp = fmaf(zs[i], zs[i], fmaf(ys[i], ys[i], xs[i] * xs[i]));
      const int n = g * 1024 + tid * 4 + i;
#pragma unroll
      for (int k = 0; k < QB; k++) {
        float t = fmaf(xs[i], qx2[k], pp);
        t = fmaf(ys[i], qy2[k], t);
        t = fmaf(zs[i], qz2[k], t);
        if (t <= th2[k]) {
          int pos = atomicAdd(&cnt[k], 1);
          if (pos < CAPQ) candI[k][pos] = (unsigned)n;
        }
      }
    }
  }
  __syncthreads();

  // ---- Rank phase: exact distance + stable (d_bits, idx) rank per query ----
  const float* __restrict__ baseF = xyz + (size_t)b * NN_ * 3;
#pragma unroll
  for (int t2 = 0; t2 < 2; t2++) {
    const int k = wid * 2 + t2;
    const int qq = q0 + k;
    const int m = cnt[k] < CAPQ ? cnt[k] : CAPQ;
    // raw query coords (bit-exact reference values)
    const float qxk = new_xyz[qq * 3 + 0];
    const float qyk = new_xyz[qq * 3 + 1];
    const float qzk = new_xyz[qq * 3 + 2];

    unsigned long long keyreg[CAPQ / 64];
#pragma unroll
    for (int c = 0; c < CAPQ / 64; c++) {
      const int i = lane + c * 64;
      if (i < m) {
        const int n = (int)candI[k][i];
        float dx = baseF[n * 3 + 0] - qxk;
        float dy = baseF[n * 3 + 1] - qyk;
        float dz = baseF[n * 3 + 2] - qzk;
        // bit-exact reference distance: no FMA contraction, left-to-right sum
        float d = __fadd_rn(__fadd_rn(__fmul_rn(dx, dx), __fmul_rn(dy, dy)),
                            __fmul_rn(dz, dz));
        keyreg[c] = ((unsigned long long)__float_as_uint(d) << 32) | (unsigned)n;
      }
    }
    __syncthreads();   // candI fully read -> safe even if regions were reused
#pragma unroll
    for (int c = 0; c < CAPQ / 64; c++) {
      const int i = lane + c * 64;
      if (i < m) keys[k][i] = keyreg[c];
    }
    __syncthreads();   // keys visible to all lanes
#pragma unroll
    for (int c = 0; c < CAPQ / 64; c++) {
      const int i = lane + c * 64;
      if (i < m) {
        unsigned long long x = keys[k][i];
        int r = 0;
        for (int j = 0; j < m; j++) r += (keys[k][j] < x) ? 1 : 0;
        if (r < NS) idxOut[qq * NS + r] = (int)(x & 0xffffffffu);
      }
    }
    __syncthreads();
  }
}

// ---------------- Phase 2: gather + grouped write ----------------
#define FSTR 68   // LDS row stride: multiple of 4 (float4 stores), 4-way bank alias only
__global__ __launch_bounds__(256) void group_kernel(const float* __restrict__ xyz,
                                                    const float* __restrict__ new_xyz,
                                                    const float* __restrict__ featsT,
                                                    const int* __restrict__ idxArr,
                                                    float* __restrict__ out) {
  const int q = blockIdx.x;            // b*NPOINT + p
  const int b = q / NPOINT;
  const int p = q - b * NPOINT;
  const int tid = threadIdx.x;

  __shared__ int sIdx[NS];
  __shared__ __align__(16) float ldsF[NS * FSTR];
  __shared__ float ldsX[3 * NS];

  if (tid < NS) sIdx[tid] = idxArr[q * NS + tid];
  __syncthreads();

  {
    // 256 threads = 32 samples x 8 readers; each reader pulls 32B of the
    // 256B contiguous feature row for its sample.
    int s = tid >> 3, r = tid & 7;
    int nn = sIdx[s];
    const float4* src = (const float4*)(featsT + ((size_t)b * NN_ + nn) * CF);
    float4 v0 = src[r * 2];
    float4 v1 = src[r * 2 + 1];
    float4* dst = (float4*)(ldsF + s * FSTR + r * 8);
    dst[0] = v0;
    dst[1] = v1;
  }
  if (tid < 96) {
    int dd = tid >> 5, s = tid & 31;
    int nn = sIdx[s];
    ldsX[dd * NS + s] = xyz[((size_t)b * NN_ + nn) * 3 + dd] -
                        new_xyz[(size_t)q * 3 + dd];
  }
  __syncthreads();

  // Write 67 rows of 32 floats (128B coalesced per row), 8 rows at a time.
  const int s = tid & 31;
  const int r0 = tid >> 5;
#pragma unroll
  for (int k = 0; k < 9; k++) {
    int row = r0 + k * 8;
    if (row < 67) {
      float v = (row < 3) ? ldsX[row * NS + s] : ldsF[s * FSTR + (row - 3)];
      out[(((size_t)b * 67 + row) * NPOINT + p) * NS + s] = v;
    }
  }
}

extern "C" void kernel_launch(void* const* d_in, const int* in_sizes, int n_in,
                              void* d_out, int out_size, void* d_ws, size_t ws_size,
                              hipStream_t stream) {
  const float* xyz      = (const float*)d_in[0];   // (4,8192,3)
  const float* new_xyz  = (const float*)d_in[1];   // (4,2048,3)
  // d_in[2], d_in[3]: components — unused (LAMBDA=0.5 makes mask a no-op)
  const float* features = (const float*)d_in[4];   // (4,64,8192)
  float* out = (float*)d_out;

  // workspace layout: [idx: 4*2048*32 int = 1MB][featsT: 4*8192*64 f32 = 8MB]
  int* idxArr = (int*)d_ws;
  float* featsT = (float*)((char*)d_ws + (size_t)BQ * NPOINT * NS * sizeof(int));

  knn_tr_kernel<<<KNN_BLOCKS + TR_BLOCKS, T1, 0, stream>>>(xyz, new_xyz, features,
                                                           idxArr, featsT);
  group_kernel<<<BQ * NPOINT, T1, 0, stream>>>(xyz, new_xyz, featsT, idxArr, out);
}